// Round 5
// baseline (390.232 us; speedup 1.0000x reference)
//
#include <hip/hip_runtime.h>

// Decoder: scores[b,m] = sum_e ( sum_d sbj[b,0,d] * W_r[rel[b]][d][e] ) * obj[b,m][e]
// B=1024, D=512, N_OBJ=64, EDGE_COUNT=200. All f32.
//
// Design (round 5): per-batch fused kernel (round-1 structure: proven 3.2 TB/s,
// fully-resident 1024-block grid) + relation-sorted dispatch with XCD-chunked
// swizzle so same-relation blocks share an XCD L2 -> W_r fetched from HBM ~once
// (~200 MB compulsory instead of round-1's 533 MB measured). float4 W loads,
// 2-way row split, exact per-batch output (no atomics, no memset).

#define D      512
#define NOBJ   64
#define EDGES  200

// ---------------- K0: sort batch indices by relation ----------------
__global__ __launch_bounds__(256) void prep_kernel(
    const int* __restrict__ rel, int B, int* __restrict__ sorted)
{
    __shared__ int cnt[256];
    __shared__ int scan[256];
    __shared__ int off[256];
    __shared__ int pos[256];
    const int t = threadIdx.x;

    cnt[t] = 0; pos[t] = 0;
    __syncthreads();

    for (int b = t; b < B; b += 256) atomicAdd(&cnt[rel[b]], 1);
    __syncthreads();

    // Hillis-Steele inclusive scan over 256 bins (uniform control flow)
    int val = cnt[t];
    scan[t] = val;
    __syncthreads();
    for (int o = 1; o < 256; o <<= 1) {
        int v = (t >= o) ? scan[t - o] : 0;
        __syncthreads();
        scan[t] += v;
        __syncthreads();
    }
    off[t] = scan[t] - val;   // exclusive prefix
    __syncthreads();

    for (int b = t; b < B; b += 256) {
        const int r = rel[b];
        sorted[off[r] + atomicAdd(&pos[r], 1)] = b;
    }
}

// ---------------- K1: fused per-batch GEMV + score ----------------
// blockIdx -> XCD-chunked position in the relation-sorted order.
__global__ __launch_bounds__(256) void main_kernel(
    const float* __restrict__ sbj, const float* __restrict__ obj,
    const float* __restrict__ Wr,  const int* __restrict__ rel,
    const int* __restrict__ sorted, float* __restrict__ out)
{
    // Bijective XCD-chunk swizzle (m204 form): blocks dispatched round-robin
    // across 8 XCDs get contiguous chunks of the sorted order, so the ~5
    // blocks sharing one W_r run concurrently on the same XCD's L2.
    int wg;
    {
        const int nwg = gridDim.x;
        const int q = nwg >> 3, r = nwg & 7;
        const int xcd = blockIdx.x & 7, idx = blockIdx.x >> 3;
        wg = (xcd < r ? xcd * (q + 1) : r * (q + 1) + (xcd - r) * q) + idx;
    }
    const int b    = sorted[wg];
    const int t    = threadIdx.x;
    const int lane = t & 63;
    const int wv   = t >> 6;

    __shared__ float s_lds[D];        // subject (reused as v after phase 1)
    __shared__ float p_lds[2 * D];    // phase-1 partials: [row-half][col]

    // ---- load subject ----
    {
        const float2 sv = reinterpret_cast<const float2*>(sbj + (size_t)b * D)[t];
        s_lds[2 * t]     = sv.x;
        s_lds[2 * t + 1] = sv.y;
    }
    __syncthreads();

    // ---- phase 1: v[c] = sum_d s[d] * W[d][c] ----
    // thread t: 4 cols c4=(t&127)*4, row half h=t>>7 (rows h*256..h*256+255).
    // Per wave-instr: 64 lanes x 16B = 1KB contiguous W. 1MB W per block.
    const int c4 = (t & 127) << 2;
    const int h  = t >> 7;

    const float4* __restrict__ W4 =
        reinterpret_cast<const float4*>(Wr + (size_t)rel[b] * D * D)
        + (size_t)(h * 256) * (D / 4) + (c4 >> 2);
    const float* __restrict__ sp = s_lds + h * 256;

    float4 acc; acc.x = acc.y = acc.z = acc.w = 0.f;

    #pragma unroll 4
    for (int d4 = 0; d4 < 256; d4 += 4) {
        const float4 sd4 = *reinterpret_cast<const float4*>(sp + d4);  // wave-uniform b128
        const float4 w0 = W4[(size_t)(d4 + 0) * (D / 4)];
        const float4 w1 = W4[(size_t)(d4 + 1) * (D / 4)];
        const float4 w2 = W4[(size_t)(d4 + 2) * (D / 4)];
        const float4 w3 = W4[(size_t)(d4 + 3) * (D / 4)];
        acc.x = fmaf(sd4.x, w0.x, acc.x); acc.y = fmaf(sd4.x, w0.y, acc.y);
        acc.z = fmaf(sd4.x, w0.z, acc.z); acc.w = fmaf(sd4.x, w0.w, acc.w);
        acc.x = fmaf(sd4.y, w1.x, acc.x); acc.y = fmaf(sd4.y, w1.y, acc.y);
        acc.z = fmaf(sd4.y, w1.z, acc.z); acc.w = fmaf(sd4.y, w1.w, acc.w);
        acc.x = fmaf(sd4.z, w2.x, acc.x); acc.y = fmaf(sd4.z, w2.y, acc.y);
        acc.z = fmaf(sd4.z, w2.z, acc.z); acc.w = fmaf(sd4.z, w2.w, acc.w);
        acc.x = fmaf(sd4.w, w3.x, acc.x); acc.y = fmaf(sd4.w, w3.y, acc.y);
        acc.z = fmaf(sd4.w, w3.z, acc.z); acc.w = fmaf(sd4.w, w3.w, acc.w);
    }

    reinterpret_cast<float4*>(p_lds)[h * 128 + (c4 >> 2)] = acc;
    __syncthreads();   // also guards s_lds reuse below (all sp reads done)

    // ---- combine row halves: v[c] = p[0][c] + p[1][c], store into s_lds ----
    {
        const float2 pa = *reinterpret_cast<const float2*>(p_lds + 2 * t);
        const float2 pb = *reinterpret_cast<const float2*>(p_lds + D + 2 * t);
        s_lds[2 * t]     = pa.x + pb.x;
        s_lds[2 * t + 1] = pa.y + pb.y;
    }
    __syncthreads();

    // ---- phase 2: scores[m] = dot(v, obj[b,m,:]) (round-1 proven mapping) ----
    float vreg[8];
    #pragma unroll
    for (int k = 0; k < 8; ++k) vreg[k] = s_lds[lane * 8 + k];

    const float* __restrict__ objb = obj + (size_t)b * NOBJ * D;

    #pragma unroll 4
    for (int j = 0; j < 16; ++j) {
        const int m = wv * 16 + j;
        const float4* __restrict__ o4 =
            reinterpret_cast<const float4*>(objb + (size_t)m * D);
        const float4 a = o4[lane * 2];
        const float4 c = o4[lane * 2 + 1];

        float p = vreg[0] * a.x + vreg[1] * a.y + vreg[2] * a.z + vreg[3] * a.w
                + vreg[4] * c.x + vreg[5] * c.y + vreg[6] * c.z + vreg[7] * c.w;

        #pragma unroll
        for (int off = 32; off > 0; off >>= 1)
            p += __shfl_down(p, off, 64);

        if (lane == 0) out[(size_t)b * NOBJ + m] = p;
    }
}

// ---------------- fallback (ws too small): identity order ----------------
__global__ __launch_bounds__(256) void fused_kernel(
    const float* __restrict__ sbj, const float* __restrict__ obj,
    const int* __restrict__ rel, const float* __restrict__ Wr,
    float* __restrict__ out)
{
    const int b = blockIdx.x;
    const int t = threadIdx.x;
    __shared__ float s_lds[D];
    __shared__ float v_lds[D];
    {
        const float2 sv = reinterpret_cast<const float2*>(sbj + (size_t)b * D)[t];
        s_lds[2 * t] = sv.x; s_lds[2 * t + 1] = sv.y;
    }
    __syncthreads();
    const float2* __restrict__ W2 = reinterpret_cast<const float2*>(Wr + (size_t)rel[b] * D * D);
    float acc0 = 0.f, acc1 = 0.f;
    #pragma unroll 8
    for (int d = 0; d < D; ++d) {
        const float sd = s_lds[d];
        const float2 w = W2[d * (D / 2) + t];
        acc0 = fmaf(sd, w.x, acc0); acc1 = fmaf(sd, w.y, acc1);
    }
    v_lds[2 * t] = acc0; v_lds[2 * t + 1] = acc1;
    __syncthreads();
    const int wave = t >> 6, lane = t & 63;
    float vreg[8];
    #pragma unroll
    for (int k = 0; k < 8; ++k) vreg[k] = v_lds[lane * 8 + k];
    const float* __restrict__ objb = obj + (size_t)b * NOBJ * D;
    #pragma unroll 4
    for (int j = 0; j < 16; ++j) {
        const int mm = wave * 16 + j;
        const float4* __restrict__ o4 = reinterpret_cast<const float4*>(objb + (size_t)mm * D);
        const float4 a = o4[lane * 2];
        const float4 c = o4[lane * 2 + 1];
        float p = vreg[0]*a.x + vreg[1]*a.y + vreg[2]*a.z + vreg[3]*a.w
                + vreg[4]*c.x + vreg[5]*c.y + vreg[6]*c.z + vreg[7]*c.w;
        #pragma unroll
        for (int off = 32; off > 0; off >>= 1) p += __shfl_down(p, off, 64);
        if (lane == 0) out[(size_t)b * NOBJ + mm] = p;
    }
}

extern "C" void kernel_launch(void* const* d_in, const int* in_sizes, int n_in,
                              void* d_out, int out_size, void* d_ws, size_t ws_size,
                              hipStream_t stream) {
    const float* sbj = (const float*)d_in[0];   // [B,1,512]
    const float* obj = (const float*)d_in[1];   // [B,64,512]
    const int*   rel = (const int*)d_in[2];     // [B]
    const float* Wr  = (const float*)d_in[3];   // [200,512,512]
    float*       out = (float*)d_out;           // [B,64]
    const int B = in_sizes[2];

    if (ws_size < (size_t)B * 4) {
        fused_kernel<<<dim3(B), dim3(256), 0, stream>>>(sbj, obj, rel, Wr, out);
        return;
    }

    int* sorted = (int*)d_ws;
    prep_kernel<<<dim3(1), dim3(256), 0, stream>>>(rel, B, sorted);
    main_kernel<<<dim3(B), dim3(256), 0, stream>>>(sbj, obj, Wr, rel, sorted, out);
}